// Round 1
// baseline (724.258 us; speedup 1.0000x reference)
//
#include <hip/hip_runtime.h>
#include <math.h>

// Problem constants
#define HW 4096          // 64*64 latent positions
#define C 320            // channels
#define CX 768           // encoder channels
#define L 77             // encoder seq len
#define NB 10            // batches after concat (1 uncond + 9 cond)
#define NH 8             // heads
#define HD 40            // head dim
#define NINST 8          // bboxes
#define SCALE 0.15811388300841898f  // 1/sqrt(40)

// ---------------------------------------------------------------------------
// Mask / phase-weight kernel: replicate jax.image.resize bilinear+antialias
// (triangle kernel, downscale 512->64, 16 taps, sample_f = 8*o + 3.5),
// exploiting separability of the box mask.
// ---------------------------------------------------------------------------
__device__ __forceinline__ float axis_profile(int o, float lo, float hi) {
    // taps j = 8o-4 .. 8o+11, weight 1 - |(t - 7.5)| / 8, normalized over valid j
    float num = 0.f, den = 0.f;
    int j0 = 8 * o - 4;
#pragma unroll
    for (int t = 0; t < 16; ++t) {
        int j = j0 + t;
        float wt = 1.0f - fabsf((float)t - 7.5f) * 0.125f;
        if (j >= 0 && j < 512) {
            den += wt;
            float fj = (float)j;
            if (fj >= lo && fj < hi) num += wt;
        }
    }
    return num / den;
}

__global__ void maskw_kernel(const float* __restrict__ bboxes,  // (8,4) x0,y0,x1,y1
                             float* __restrict__ wPh,           // (9, HW)
                             float* __restrict__ wSum) {        // (HW)
    int hw = blockIdx.x * 256 + threadIdx.x;
    if (hw >= HW) return;
    int oy = hw >> 6, ox = hw & 63;
    float sum = 0.1f;
    wPh[hw] = 0.1f;
#pragma unroll
    for (int n = 0; n < NINST; ++n) {
        float x0 = bboxes[n * 4 + 0];
        float y0 = bboxes[n * 4 + 1];
        float x1 = bboxes[n * 4 + 2];
        float y1 = bboxes[n * 4 + 3];
        float w_min = floorf(512.f * x0);
        float h_min = floorf(512.f * y0);
        float w_max = floorf(512.f * x1);
        float h_max = floorf(512.f * y1);
        float sh = axis_profile(oy, h_min, h_max);
        float sw = axis_profile(ox, w_min, w_max);
        float wv = 10.f * sh * sw;
        wPh[(n + 1) * HW + hw] = wv;
        sum += wv;
    }
    wSum[hw] = sum;
}

// ---------------------------------------------------------------------------
// Generic fp32 tiled GEMM: C[M,N] = A[M,K] @ B[K,N]
// 64x64 tile, BK=16, 256 threads, 4x4 microtile. N must be a multiple of 64,
// K a multiple of 16; M guarded.
// ---------------------------------------------------------------------------
#define TS 64
#define KT 16
#define LDP (TS + 4)

__global__ __launch_bounds__(256) void gemm_f32(const float* __restrict__ A,
                                                const float* __restrict__ B,
                                                float* __restrict__ Cm,
                                                int M, int N, int K) {
    __shared__ float As[KT][LDP];
    __shared__ float Bs[KT][LDP];
    int tid = threadIdx.x;
    int tx = tid & 15, ty = tid >> 4;
    int row0 = blockIdx.y * TS, col0 = blockIdx.x * TS;
    float acc[4][4] = {{0.f}};

    for (int k0 = 0; k0 < K; k0 += KT) {
        {   // A tile: 64 rows x 16 k, thread loads float4 along k
            int m = tid & 63;
            int kk = (tid >> 6) << 2;  // 0,4,8,12
            int gr = row0 + m;
            float4 a4 = make_float4(0.f, 0.f, 0.f, 0.f);
            if (gr < M) a4 = *(const float4*)(A + (size_t)gr * K + k0 + kk);
            As[kk + 0][m] = a4.x;
            As[kk + 1][m] = a4.y;
            As[kk + 2][m] = a4.z;
            As[kk + 3][m] = a4.w;
        }
        {   // B tile: 16 k x 64 n, coalesced float4 along n
            int n = (tid & 15) << 2;
            int kk = tid >> 4;
            float4 b4 = *(const float4*)(B + (size_t)(k0 + kk) * N + col0 + n);
            *(float4*)&Bs[kk][n] = b4;
        }
        __syncthreads();
#pragma unroll
        for (int kk = 0; kk < KT; ++kk) {
            float4 a = *(const float4*)&As[kk][ty << 2];
            float4 b = *(const float4*)&Bs[kk][tx << 2];
            acc[0][0] = fmaf(a.x, b.x, acc[0][0]);
            acc[0][1] = fmaf(a.x, b.y, acc[0][1]);
            acc[0][2] = fmaf(a.x, b.z, acc[0][2]);
            acc[0][3] = fmaf(a.x, b.w, acc[0][3]);
            acc[1][0] = fmaf(a.y, b.x, acc[1][0]);
            acc[1][1] = fmaf(a.y, b.y, acc[1][1]);
            acc[1][2] = fmaf(a.y, b.z, acc[1][2]);
            acc[1][3] = fmaf(a.y, b.w, acc[1][3]);
            acc[2][0] = fmaf(a.z, b.x, acc[2][0]);
            acc[2][1] = fmaf(a.z, b.y, acc[2][1]);
            acc[2][2] = fmaf(a.z, b.z, acc[2][2]);
            acc[2][3] = fmaf(a.z, b.w, acc[2][3]);
            acc[3][0] = fmaf(a.w, b.x, acc[3][0]);
            acc[3][1] = fmaf(a.w, b.y, acc[3][1]);
            acc[3][2] = fmaf(a.w, b.z, acc[3][2]);
            acc[3][3] = fmaf(a.w, b.w, acc[3][3]);
        }
        __syncthreads();
    }
#pragma unroll
    for (int i = 0; i < 4; ++i) {
        int row = row0 + (ty << 2) + i;
        if (row < M) {
            float4 v = make_float4(acc[i][0], acc[i][1], acc[i][2], acc[i][3]);
            *(float4*)(Cm + (size_t)row * N + col0 + (tx << 2)) = v;
        }
    }
}

// ---------------------------------------------------------------------------
// O-projection GEMM with fused epilogue:
//   rows 0..4095   : out = val + bo[c]
//   rows 4096..8191: out = (val + bo[c]*wSum[hw]) / (wSum[hw] + 1e-6)
// M = 8192, N = K = 320.
// ---------------------------------------------------------------------------
__global__ __launch_bounds__(256) void gemm_oproj(const float* __restrict__ A,
                                                  const float* __restrict__ B,
                                                  const float* __restrict__ bo,
                                                  const float* __restrict__ wSum,
                                                  float* __restrict__ Out) {
    const int M = 2 * HW, N = C, K = C;
    __shared__ float As[KT][LDP];
    __shared__ float Bs[KT][LDP];
    int tid = threadIdx.x;
    int tx = tid & 15, ty = tid >> 4;
    int row0 = blockIdx.y * TS, col0 = blockIdx.x * TS;
    float acc[4][4] = {{0.f}};

    for (int k0 = 0; k0 < K; k0 += KT) {
        {
            int m = tid & 63;
            int kk = (tid >> 6) << 2;
            int gr = row0 + m;
            float4 a4 = *(const float4*)(A + (size_t)gr * K + k0 + kk);
            As[kk + 0][m] = a4.x;
            As[kk + 1][m] = a4.y;
            As[kk + 2][m] = a4.z;
            As[kk + 3][m] = a4.w;
        }
        {
            int n = (tid & 15) << 2;
            int kk = tid >> 4;
            float4 b4 = *(const float4*)(B + (size_t)(k0 + kk) * N + col0 + n);
            *(float4*)&Bs[kk][n] = b4;
        }
        __syncthreads();
#pragma unroll
        for (int kk = 0; kk < KT; ++kk) {
            float4 a = *(const float4*)&As[kk][ty << 2];
            float4 b = *(const float4*)&Bs[kk][tx << 2];
            acc[0][0] = fmaf(a.x, b.x, acc[0][0]);
            acc[0][1] = fmaf(a.x, b.y, acc[0][1]);
            acc[0][2] = fmaf(a.x, b.z, acc[0][2]);
            acc[0][3] = fmaf(a.x, b.w, acc[0][3]);
            acc[1][0] = fmaf(a.y, b.x, acc[1][0]);
            acc[1][1] = fmaf(a.y, b.y, acc[1][1]);
            acc[1][2] = fmaf(a.y, b.z, acc[1][2]);
            acc[1][3] = fmaf(a.y, b.w, acc[1][3]);
            acc[2][0] = fmaf(a.z, b.x, acc[2][0]);
            acc[2][1] = fmaf(a.z, b.y, acc[2][1]);
            acc[2][2] = fmaf(a.z, b.z, acc[2][2]);
            acc[2][3] = fmaf(a.z, b.w, acc[2][3]);
            acc[3][0] = fmaf(a.w, b.x, acc[3][0]);
            acc[3][1] = fmaf(a.w, b.y, acc[3][1]);
            acc[3][2] = fmaf(a.w, b.z, acc[3][2]);
            acc[3][3] = fmaf(a.w, b.w, acc[3][3]);
        }
        __syncthreads();
    }

    int colb = col0 + (tx << 2);
    float4 bov = *(const float4*)(bo + colb);
#pragma unroll
    for (int i = 0; i < 4; ++i) {
        int row = row0 + (ty << 2) + i;
        float4 v = make_float4(acc[i][0], acc[i][1], acc[i][2], acc[i][3]);
        if (row < HW) {
            v.x += bov.x; v.y += bov.y; v.z += bov.z; v.w += bov.w;
        } else {
            float ws = wSum[row - HW];
            float rinv = 1.0f / (ws + 1e-6f);
            v.x = (v.x + bov.x * ws) * rinv;
            v.y = (v.y + bov.y * ws) * rinv;
            v.z = (v.z + bov.z * ws) * rinv;
            v.w = (v.w + bov.w * ws) * rinv;
        }
        *(float4*)(Out + (size_t)row * N + colb) = v;
    }
}

// ---------------------------------------------------------------------------
// Attention: per (head, 128-row tile, part). part 0 -> batch 0 (write X rows
// 0..4095). part 1 -> batches 1..9, phase-weighted sum (write X rows
// 4096..8191). Light/heavy parts interleaved via blockIdx.x&1 for balance.
// One thread = one query row. Keys/values staged in LDS (broadcast reads).
// Logits are ~N(0,0.2) -> exp without max-subtraction is safe in fp32.
// ---------------------------------------------------------------------------
__global__ __launch_bounds__(128) void attn_kernel(const float* __restrict__ Q,   // (8192,320)
                                                   const float* __restrict__ Kb,  // (770,320)
                                                   const float* __restrict__ Vb,  // (770,320)
                                                   const float* __restrict__ wPh, // (9,HW)
                                                   float* __restrict__ X) {       // (8192,320)
    __shared__ float ks[L][HD];
    __shared__ float vs[L][HD];
    int bx = blockIdx.x;
    int zpart = bx & 1;
    int rest = bx >> 1;       // 0..255
    int head = rest >> 5;     // 0..7
    int tile = rest & 31;     // 0..31
    int row = tile * 128 + threadIdx.x;  // 0..4095

    const float* qp = Q + (size_t)(zpart ? (HW + row) : row) * C + head * HD;
    float q[HD];
#pragma unroll
    for (int i = 0; i < HD / 4; ++i) {
        float4 t = ((const float4*)qp)[i];
        q[4 * i + 0] = t.x; q[4 * i + 1] = t.y; q[4 * i + 2] = t.z; q[4 * i + 3] = t.w;
    }
    float acc[HD];
#pragma unroll
    for (int i = 0; i < HD; ++i) acc[i] = 0.f;

    int b_lo = zpart ? 1 : 0;
    int b_hi = zpart ? NB : 1;
    for (int b = b_lo; b < b_hi; ++b) {
        __syncthreads();
        const float* kg = Kb + (size_t)(b * L) * C + head * HD;
        const float* vg = Vb + (size_t)(b * L) * C + head * HD;
        for (int idx = threadIdx.x; idx < L * HD; idx += 128) {
            int j = idx / HD, d = idx - j * HD;
            ks[j][d] = kg[(size_t)j * C + d];
            vs[j][d] = vg[(size_t)j * C + d];
        }
        __syncthreads();

        float l = 0.f;
        float oa[HD];
#pragma unroll
        for (int i = 0; i < HD; ++i) oa[i] = 0.f;
        for (int j = 0; j < L; ++j) {
            float s0 = 0.f, s1 = 0.f, s2 = 0.f, s3 = 0.f;
#pragma unroll
            for (int d = 0; d < HD; d += 4) {
                s0 = fmaf(q[d + 0], ks[j][d + 0], s0);
                s1 = fmaf(q[d + 1], ks[j][d + 1], s1);
                s2 = fmaf(q[d + 2], ks[j][d + 2], s2);
                s3 = fmaf(q[d + 3], ks[j][d + 3], s3);
            }
            float p = __expf(((s0 + s1) + (s2 + s3)) * SCALE);
            l += p;
#pragma unroll
            for (int d = 0; d < HD; ++d) oa[d] = fmaf(p, vs[j][d], oa[d]);
        }
        float wgt = zpart ? wPh[(size_t)(b - 1) * HW + row] : 1.0f;
        float r = wgt / l;
#pragma unroll
        for (int d = 0; d < HD; ++d) acc[d] = fmaf(r, oa[d], acc[d]);
    }

    float* xp = X + (size_t)(zpart ? (HW + row) : row) * C + head * HD;
#pragma unroll
    for (int i = 0; i < HD / 4; ++i) {
        ((float4*)xp)[i] = make_float4(acc[4 * i], acc[4 * i + 1], acc[4 * i + 2], acc[4 * i + 3]);
    }
}

// ---------------------------------------------------------------------------
// Launch
// ---------------------------------------------------------------------------
extern "C" void kernel_launch(void* const* d_in, const int* in_sizes, int n_in,
                              void* d_out, int out_size, void* d_ws, size_t ws_size,
                              hipStream_t stream) {
    const float* hs   = (const float*)d_in[0];  // (2,4096,320) -> flat (8192,320)
    const float* ehs  = (const float*)d_in[1];  // (11,77,768) -> use first 770 rows
    const float* bbox = (const float*)d_in[2];  // (1,8,4)
    const float* Wq   = (const float*)d_in[3];  // (320,320)
    const float* Wk   = (const float*)d_in[4];  // (768,320)
    const float* Wv   = (const float*)d_in[5];  // (768,320)
    const float* Wo   = (const float*)d_in[6];  // (320,320)
    const float* bo   = (const float*)d_in[7];  // (320)
    float* out = (float*)d_out;                 // (2,4096,320)

    float* Qbuf = (float*)d_ws;                 // 8192*320
    float* Kbuf = Qbuf + (size_t)2 * HW * C;    // 770*320
    float* Vbuf = Kbuf + (size_t)NB * L * C;    // 770*320
    float* Xbuf = Vbuf + (size_t)NB * L * C;    // 8192*320
    float* wPh  = Xbuf + (size_t)2 * HW * C;    // 9*4096
    float* wSum = wPh + (size_t)(NINST + 1) * HW;

    maskw_kernel<<<dim3(HW / 256), 256, 0, stream>>>(bbox, wPh, wSum);
    gemm_f32<<<dim3(C / TS, (2 * HW) / TS), 256, 0, stream>>>(hs, Wq, Qbuf, 2 * HW, C, C);
    gemm_f32<<<dim3(C / TS, (NB * L + TS - 1) / TS), 256, 0, stream>>>(ehs, Wk, Kbuf, NB * L, C, CX);
    gemm_f32<<<dim3(C / TS, (NB * L + TS - 1) / TS), 256, 0, stream>>>(ehs, Wv, Vbuf, NB * L, C, CX);
    attn_kernel<<<dim3(512), 128, 0, stream>>>(Qbuf, Kbuf, Vbuf, wPh, Xbuf);
    gemm_oproj<<<dim3(C / TS, (2 * HW) / TS), 256, 0, stream>>>(Xbuf, Wo, bo, wSum, out);
}